// Round 15
// baseline (207.161 us; speedup 1.0000x reference)
//
#include <hip/hip_runtime.h>

typedef unsigned short bfu;
typedef __attribute__((ext_vector_type(8))) short short8;
typedef __attribute__((ext_vector_type(4))) float f32x4;

#define TT 2048
#define EE 2048

// Raw barrier without the vmcnt(0) drain __syncthreads would emit.
#define GBAR() do { __builtin_amdgcn_sched_barrier(0); \
                    __builtin_amdgcn_s_barrier();      \
                    __builtin_amdgcn_sched_barrier(0); } while (0)

__device__ __forceinline__ unsigned short f2bf(float f) {
  union { float fv; unsigned int u; } v; v.fv = f;
  unsigned int r = v.u + 0x7fffu + ((v.u >> 16) & 1u);
  return (unsigned short)(r >> 16);
}

// Native packed f32->bf16 (RNE): D.lo = bf16(lo), D.hi = bf16(hi).
__device__ __forceinline__ unsigned int cvtpk(float lo, float hi) {
  unsigned int r;
  asm("v_cvt_pk_bf16_f32 %0, %1, %2" : "=v"(r) : "v"(lo), "v"(hi));
  return r;
}

// Single-instruction exp2 (v_exp_f32 IS 2^x); x <= 0 here, -1e30 -> 0.
__device__ __forceinline__ float fexp2(float x) {
  float r;
  asm("v_exp_f32 %0, %1" : "=v"(r) : "v"(x));
  return r;
}

__device__ __forceinline__ void gload16(const void* g, void* l) {
  __builtin_amdgcn_global_load_lds(
      (const __attribute__((address_space(1))) unsigned int*)g,
      (__attribute__((address_space(3))) unsigned int*)l, 16, 0, 0);
}

// Fused f32->bf16 conversion (y<5) + block-mask canonicalization (y==5).
__global__ __launch_bounds__(256) void cvt5(
    const float* __restrict__ s0, const float* __restrict__ s1,
    const float* __restrict__ s2, const float* __restrict__ s3,
    const float* __restrict__ s4,
    bfu* __restrict__ d0, bfu* __restrict__ d1, bfu* __restrict__ d2,
    bfu* __restrict__ d3, bfu* __restrict__ d4,
    const unsigned char* __restrict__ mask_in, unsigned char* __restrict__ mask_out) {
  if (blockIdx.y == 5) {
    if (blockIdx.x != 0) return;
    __shared__ int mis;
    if (threadIdx.x == 0) mis = 0;
    __syncthreads();
    int any = 0;
    for (int i = threadIdx.x; i < 1024; i += 256)
      if ((i & 3) != 0 && mask_in[i] != 0) any = 1;
    if (any) atomicAdd(&mis, 1);
    __syncthreads();
    for (int i = threadIdx.x; i < 1024; i += 256) {
      if (mis == 0) mask_out[i] = (((const int*)mask_in)[i] != 0) ? 1 : 0;  // int32 storage
      else          mask_out[i] = mask_in[i] ? 1 : 0;                       // u8/bool storage
    }
    return;
  }
  const float* s; bfu* d; int n;
  switch (blockIdx.y) {
    case 0:  s = s0; d = d0; n = 4194304; break;
    case 1:  s = s1; d = d1; n = 4194304; break;
    case 2:  s = s2; d = d2; n = 1048576; break;
    case 3:  s = s3; d = d3; n = 1048576; break;
    default: s = s4; d = d4; n = 4194304; break;
  }
  for (int i = (blockIdx.x * 256 + threadIdx.x) * 8; i < n; i += 512 * 256 * 8) {
    float4 a = *(const float4*)(s + i);
    float4 b = *(const float4*)(s + i + 4);
    short8 pk;
    pk[0] = (short)f2bf(a.x); pk[1] = (short)f2bf(a.y);
    pk[2] = (short)f2bf(a.z); pk[3] = (short)f2bf(a.w);
    pk[4] = (short)f2bf(b.x); pk[5] = (short)f2bf(b.y);
    pk[6] = (short)f2bf(b.z); pk[7] = (short)f2bf(b.w);
    *(short8*)(d + i) = pk;
  }
}

// Fused Q/K/V projection: 64x128 tile, 8 waves (512 thr), wave = 16x64.
// grid (24,32) = 768 blocks = 3/CU, 24 waves/CU. Swizzled LDS, counted-vmcnt.
__global__ __launch_bounds__(512) void gemm_qkv(
    const bfu* __restrict__ A, const bfu* __restrict__ Bq,
    const bfu* __restrict__ Bk, const bfu* __restrict__ Bv,
    bfu* __restrict__ qr, bfu* __restrict__ kro, bfu* __restrict__ vt,
    const float* __restrict__ cosb, const float* __restrict__ sinb, float qsc) {
  __shared__ bfu As[2][64 * 64];    // 16 KB
  __shared__ bfu Bs[2][128 * 64];   // 32 KB
  const int bx = blockIdx.x;
  int path, n0;
  const bfu* B;
  if (bx < 16)      { path = 0; B = Bq; n0 = bx * 128; }
  else if (bx < 20) { path = 1; B = Bk; n0 = (bx - 16) * 128; }
  else              { path = 2; B = Bv; n0 = (bx - 20) * 128; }
  const int t = threadIdx.x;
  const int wid = t >> 6, lane = t & 63;
  const int wr = wid >> 1, wc = wid & 1;   // wave = rows wr*16.., cols wc*64..
  const int lr = lane & 15, lh = lane >> 4;
  const int m0 = blockIdx.y * 64;
  const int K = EE;
  f32x4 acc[4] = {};

  // A: chunk t (512 total); B: chunks t and t+512. 3 gload16 per thread.
  const int srow = t >> 3, sslot = t & 7;
  const int browB = (t + 512) >> 3, sslotB = (t + 512) & 7;
  auto stage = [&](int buf, int k0) {
    gload16(A + (size_t)(m0 + srow) * K + k0 + ((sslot ^ (srow & 7)) * 8),
            &As[buf][wid * 512]);
    gload16(B + (size_t)(n0 + srow) * K + k0 + ((sslot ^ (srow & 7)) * 8),
            &Bs[buf][wid * 512]);
    gload16(B + (size_t)(n0 + browB) * K + k0 + ((sslotB ^ (browB & 7)) * 8),
            &Bs[buf][4096 + wid * 512]);
  };

  stage(0, 0);
  for (int kt = 0; kt < 32; ++kt) {
    const int cur = kt & 1;
    if (kt < 31) {
      stage(cur ^ 1, (kt + 1) * 64);
      asm volatile("s_waitcnt vmcnt(3)" ::: "memory");  // cur tile's 3 loads done
    } else {
      asm volatile("s_waitcnt vmcnt(0)" ::: "memory");
    }
    GBAR();  // buf[cur] visible; prefetch stays in flight
    #pragma unroll
    for (int ks = 0; ks < 2; ++ks) {
      short8 a, b[4];
      a = *(const short8*)(&As[cur][(wr * 16 + lr) * 64 +
                                    (((ks * 4 + lh) ^ (lr & 7)) * 8)]);
      #pragma unroll
      for (int n = 0; n < 4; ++n)
        b[n] = *(const short8*)(&Bs[cur][(wc * 64 + n * 16 + lr) * 64 +
                                         (((ks * 4 + lh) ^ (lr & 7)) * 8)]);
      #pragma unroll
      for (int n = 0; n < 4; ++n)
        acc[n] = __builtin_amdgcn_mfma_f32_16x16x32_bf16(a, b[n], acc[n], 0, 0, 0);
    }
    GBAR();  // all waves done reading buf[cur]
  }
  #pragma unroll
  for (int r = 0; r < 4; ++r) {
    const int row = m0 + wr * 16 + lh * 4 + r;
    #pragma unroll
    for (int n = 0; n < 4; ++n) {
      const int col = n0 + wc * 64 + n * 16 + lr;
      float x = acc[n][r];
      if (path == 2) {
        vt[((size_t)(row >> 6) * 512 + col) * 64 + (row & 63)] = f2bf(x);
      } else {
        const int d = col & 63;
        float xp = (n < 2) ? -acc[n + 2][r] : acc[n - 2][r];
        float c = cosb[row * 64 + d], s = sinb[row * 64 + d];
        float sc = (path == 0) ? qsc : 1.0f;
        bfu* dst = (path == 0) ? qr : kro;
        dst[((size_t)(col >> 6) * TT + row) * 64 + d] = f2bf((x * c + xp * s) * sc);
      }
    }
  }
}

// O-projection: 64x128 tile, 8 waves, grid (16,32) = 512 blocks.
__global__ __launch_bounds__(512) void gemm_o(
    const bfu* __restrict__ A, const bfu* __restrict__ B,
    float* __restrict__ outF, int M, int N, int K) {
  __shared__ bfu As[2][64 * 64];
  __shared__ bfu Bs[2][128 * 64];
  const int t = threadIdx.x;
  const int wid = t >> 6, lane = t & 63;
  const int wr = wid >> 1, wc = wid & 1;
  const int lr = lane & 15, lh = lane >> 4;
  const int m0 = blockIdx.y * 64, n0 = blockIdx.x * 128;
  f32x4 acc[4] = {};

  const int srow = t >> 3, sslot = t & 7;
  const int browB = (t + 512) >> 3, sslotB = (t + 512) & 7;
  auto stage = [&](int buf, int k0) {
    gload16(A + (size_t)(m0 + srow) * K + k0 + ((sslot ^ (srow & 7)) * 8),
            &As[buf][wid * 512]);
    gload16(B + (size_t)(n0 + srow) * K + k0 + ((sslot ^ (srow & 7)) * 8),
            &Bs[buf][wid * 512]);
    gload16(B + (size_t)(n0 + browB) * K + k0 + ((sslotB ^ (browB & 7)) * 8),
            &Bs[buf][4096 + wid * 512]);
  };

  stage(0, 0);
  const int nk = K >> 6;
  for (int kt = 0; kt < nk; ++kt) {
    const int cur = kt & 1;
    if (kt < nk - 1) {
      stage(cur ^ 1, (kt + 1) * 64);
      asm volatile("s_waitcnt vmcnt(3)" ::: "memory");
    } else {
      asm volatile("s_waitcnt vmcnt(0)" ::: "memory");
    }
    GBAR();
    #pragma unroll
    for (int ks = 0; ks < 2; ++ks) {
      short8 a, b[4];
      a = *(const short8*)(&As[cur][(wr * 16 + lr) * 64 +
                                    (((ks * 4 + lh) ^ (lr & 7)) * 8)]);
      #pragma unroll
      for (int n = 0; n < 4; ++n)
        b[n] = *(const short8*)(&Bs[cur][(wc * 64 + n * 16 + lr) * 64 +
                                         (((ks * 4 + lh) ^ (lr & 7)) * 8)]);
      #pragma unroll
      for (int n = 0; n < 4; ++n)
        acc[n] = __builtin_amdgcn_mfma_f32_16x16x32_bf16(a, b[n], acc[n], 0, 0, 0);
    }
    GBAR();
  }
  #pragma unroll
  for (int r = 0; r < 4; ++r) {
    const int row = m0 + wr * 16 + lh * 4 + r;
    #pragma unroll
    for (int n = 0; n < 4; ++n)
      outF[(size_t)row * N + n0 + wc * 64 + n * 16 + lr] = acc[n][r];
  }
}

// Flash attention, BARRIER-FREE: K/V fragments loaded directly from L2 into
// registers (K issued first, V second -> compiler's counted vmcnt waits K for
// QK while V latency hides under QK+softmax). P in wave-private LDS (no
// barrier). Swapped-QK in-lane softmax, raw v_exp, ones-MFMA denominator.
__global__ __launch_bounds__(256, 4) void attn_kernel(
    const bfu* __restrict__ qr, const bfu* __restrict__ kr,
    const bfu* __restrict__ vt, const unsigned char* __restrict__ allow,
    bfu* __restrict__ ao) {
  const int qb = blockIdx.x, h = blockIdx.y, kv = h >> 2;
  const int t = threadIdx.x, wid = t >> 6, lane = t & 63;
  const int lr = lane & 15, lh = lane >> 4;
  const int q0 = qb * 64;
  const int qrow = q0 + wid * 16 + lr;
  __shared__ bfu P[4][16 * 64];   // 8 KB total, wave-private slices
  bfu* Pw = P[wid];

  unsigned int amask = 0, emask = 0;
  for (int kb = 0; kb < 32; ++kb) {
    bool bm = allow[qb * 32 + kb] != 0;
    bool fw = (kb < 4) || (kb >= qb - 3 && kb <= qb - 1);
    bool ed = (kb == qb) || (kb == qb - 4);
    if (bm || fw || ed) {
      amask |= 1u << kb;
      if (!bm && !fw) emask |= 1u << kb;
    }
  }

  short8 bq[2];
  #pragma unroll
  for (int ks = 0; ks < 2; ++ks)
    bq[ks] = *(const short8*)(qr + ((size_t)h * TT + qrow) * 64 + ks * 32 + lh * 8);

  short8 vones;
  #pragma unroll
  for (int i = 0; i < 8; ++i) vones[i] = (short)0x3F80;  // bf16 1.0

  f32x4 o[4] = {};
  f32x4 o_l = {};
  float m_reg = -1e30f;

  unsigned int am = amask;
  while (am) {
    const int k1 = __ffs(am) - 1; am &= am - 1;
    const bfu* kt_ = kr + ((size_t)kv * TT + k1 * 64) * 64;   // rows of 128B
    const bfu* vt_ = vt + ((size_t)k1 * 512 + kv * 64) * 64;  // rows of 128B

    // K first (QK waits on these), V second (covered by QK+softmax).
    short8 kf[8], vf[8];
    #pragma unroll
    for (int j = 0; j < 4; ++j) {
      const int row = j * 16 + lr;
      kf[2 * j]     = *(const short8*)(kt_ + row * 64 + lh * 8);
      kf[2 * j + 1] = *(const short8*)(kt_ + row * 64 + 32 + lh * 8);
    }
    #pragma unroll
    for (int n = 0; n < 4; ++n) {
      const int row = n * 16 + lr;
      vf[2 * n]     = *(const short8*)(vt_ + row * 64 + lh * 8);
      vf[2 * n + 1] = *(const short8*)(vt_ + row * 64 + 32 + lh * 8);
    }

    f32x4 s1[4];
    __builtin_amdgcn_s_setprio(1);
    #pragma unroll
    for (int j = 0; j < 4; ++j) {
      f32x4 z = {};
      z = __builtin_amdgcn_mfma_f32_16x16x32_bf16(kf[2 * j], bq[0], z, 0, 0, 0);
      s1[j] = __builtin_amdgcn_mfma_f32_16x16x32_bf16(kf[2 * j + 1], bq[1], z, 0, 0, 0);
    }
    __builtin_amdgcn_s_setprio(0);

    if ((emask >> k1) & 1) {
      #pragma unroll
      for (int j = 0; j < 4; ++j)
        #pragma unroll
        for (int reg = 0; reg < 4; ++reg) {
          int k = k1 * 64 + j * 16 + lh * 4 + reg;
          bool ok = (k <= qrow && k >= qrow - 255) || (k < 256);
          if (!ok) s1[j][reg] = -1e30f;
        }
    }

    float mx = fmaxf(fmaxf(s1[0][0], s1[0][1]), fmaxf(s1[0][2], s1[0][3]));
    #pragma unroll
    for (int j = 1; j < 4; ++j)
      mx = fmaxf(mx, fmaxf(fmaxf(s1[j][0], s1[j][1]), fmaxf(s1[j][2], s1[j][3])));
    mx = fmaxf(mx, __shfl_xor(mx, 16));
    mx = fmaxf(mx, __shfl_xor(mx, 32));

    if (__any(mx > m_reg)) {
      float mnew = fmaxf(m_reg, mx);
      float corr = fexp2(m_reg - mnew);
      m_reg = mnew;
      #pragma unroll
      for (int r = 0; r < 4; ++r) {
        float cr = __shfl(corr, lh * 4 + r);
        #pragma unroll
        for (int n = 0; n < 4; ++n) o[n][r] *= cr;
        o_l[r] *= cr;
      }
    }

    #pragma unroll
    for (int j = 0; j < 4; ++j)
      #pragma unroll
      for (int reg = 0; reg < 4; ++reg)
        s1[j][reg] = fexp2(s1[j][reg] - m_reg);

    // P pack -> wave-private LDS -> A-frag read (no barrier needed).
    #pragma unroll
    for (int j = 0; j < 4; ++j) {
      unsigned int w0 = cvtpk(s1[j][0], s1[j][1]);
      unsigned int w1 = cvtpk(s1[j][2], s1[j][3]);
      int base = lr * 64 + (((j * 2 + (lh >> 1)) ^ (lr & 7)) * 8) + (lh & 1) * 4;
      *(unsigned int*)(Pw + base) = w0;
      *(unsigned int*)(Pw + base + 2) = w1;
    }
    short8 pa[2];
    #pragma unroll
    for (int ks = 0; ks < 2; ++ks)
      pa[ks] = *(const short8*)(Pw + lr * 64 + (((ks * 4 + lh) ^ (lr & 7)) * 8));

    __builtin_amdgcn_s_setprio(1);
    #pragma unroll
    for (int n = 0; n < 4; ++n) {
      #pragma unroll
      for (int ks = 0; ks < 2; ++ks)
        o[n] = __builtin_amdgcn_mfma_f32_16x16x32_bf16(pa[ks], vf[2 * n + ks], o[n], 0, 0, 0);
    }
    o_l = __builtin_amdgcn_mfma_f32_16x16x32_bf16(pa[0], vones, o_l, 0, 0, 0);
    o_l = __builtin_amdgcn_mfma_f32_16x16x32_bf16(pa[1], vones, o_l, 0, 0, 0);
    __builtin_amdgcn_s_setprio(0);
  }

  #pragma unroll
  for (int r = 0; r < 4; ++r) {
    float inv = 1.0f / o_l[r];
    #pragma unroll
    for (int n = 0; n < 4; ++n) {
      float val = o[n][r] * inv;
      ao[(size_t)(q0 + wid * 16 + lh * 4 + r) * EE + h * 64 + n * 16 + lr] = f2bf(val);
    }
  }
}

extern "C" void kernel_launch(void* const* d_in, const int* in_sizes, int n_in,
                              void* d_out, int out_size, void* d_ws, size_t ws_size,
                              hipStream_t stream) {
  const float* hs   = (const float*)d_in[0];
  const float* cosb = (const float*)d_in[1];
  const float* sinb = (const float*)d_in[2];
  const float* Wq   = (const float*)d_in[3];
  const float* Wk   = (const float*)d_in[4];
  const float* Wv   = (const float*)d_in[5];
  const float* Wo   = (const float*)d_in[6];
  const unsigned char* allow_raw = (const unsigned char*)d_in[7];
  float* out = (float*)d_out;

  char* ws = (char*)d_ws;
  const size_t MB = 1024 * 1024;
  bfu* hsb = (bfu*)(ws);            // [2048][2048] 8 MB (reused as ao later)
  bfu* wqb = (bfu*)(ws + 8 * MB);   // 8 MB
  bfu* wkb = (bfu*)(ws + 16 * MB);  // 2 MB
  bfu* wvb = (bfu*)(ws + 18 * MB);  // 2 MB
  bfu* wob = (bfu*)(ws + 20 * MB);  // 8 MB
  bfu* qr  = (bfu*)(ws + 28 * MB);  // [32][2048][64] 8 MB
  bfu* kr  = (bfu*)(ws + 36 * MB);  // [8][2048][64]  2 MB
  bfu* vt  = (bfu*)(ws + 38 * MB);  // [32][512][64]  2 MB (tile-major)
  unsigned char* maskc = (unsigned char*)(ws + 40 * MB);  // 1 KB
  bfu* ao = hsb;

  cvt5<<<dim3(512, 6), 256, 0, stream>>>(hs, Wq, Wk, Wv, Wo,
                                         hsb, wqb, wkb, wvb, wob,
                                         allow_raw, maskc);

  const float QSC = 0.125f * 1.44269504088896f;  // head scale * log2(e)
  gemm_qkv<<<dim3(24, 32), 512, 0, stream>>>(
      hsb, wqb, wkb, wvb, qr, kr, vt, cosb, sinb, QSC);

  attn_kernel<<<dim3(32, 32), 256, 0, stream>>>(qr, kr, vt, maskc, ao);

  gemm_o<<<dim3(16, 32), 512, 0, stream>>>(ao, wob, out, 2048, 2048, 2048);
}

// Round 16
// 129.103 us; speedup vs baseline: 1.6046x; 1.6046x over previous
//
#include <hip/hip_runtime.h>

typedef unsigned short bfu;
typedef __attribute__((ext_vector_type(8))) short short8;
typedef __attribute__((ext_vector_type(4))) float f32x4;

#define TT 2048
#define EE 2048

// Raw barrier without the vmcnt(0) drain __syncthreads would emit.
#define GBAR() do { __builtin_amdgcn_sched_barrier(0); \
                    __builtin_amdgcn_s_barrier();      \
                    __builtin_amdgcn_sched_barrier(0); } while (0)

__device__ __forceinline__ unsigned short f2bf(float f) {
  union { float fv; unsigned int u; } v; v.fv = f;
  unsigned int r = v.u + 0x7fffu + ((v.u >> 16) & 1u);
  return (unsigned short)(r >> 16);
}

// Native packed f32->bf16 (RNE): D.lo = bf16(lo), D.hi = bf16(hi).
__device__ __forceinline__ unsigned int cvtpk(float lo, float hi) {
  unsigned int r;
  asm("v_cvt_pk_bf16_f32 %0, %1, %2" : "=v"(r) : "v"(lo), "v"(hi));
  return r;
}

// Single-instruction exp2 (v_exp_f32 IS 2^x); x <= 0 here, -1e30 -> 0.
__device__ __forceinline__ float fexp2(float x) {
  float r;
  asm("v_exp_f32 %0, %1" : "=v"(r) : "v"(x));
  return r;
}

__device__ __forceinline__ void gload16(const void* g, void* l) {
  __builtin_amdgcn_global_load_lds(
      (const __attribute__((address_space(1))) unsigned int*)g,
      (__attribute__((address_space(3))) unsigned int*)l, 16, 0, 0);
}

// Fused f32->bf16 conversion (y<4: hs,Wq,Wk,Wv) + mask canon (y==4).
// Wo conversion rides inside attn_kernel (overlaps with attention).
__global__ __launch_bounds__(256) void cvt5(
    const float* __restrict__ s0, const float* __restrict__ s1,
    const float* __restrict__ s2, const float* __restrict__ s3,
    bfu* __restrict__ d0, bfu* __restrict__ d1, bfu* __restrict__ d2,
    bfu* __restrict__ d3,
    const unsigned char* __restrict__ mask_in, unsigned char* __restrict__ mask_out) {
  if (blockIdx.y == 4) {
    if (blockIdx.x != 0) return;
    __shared__ int mis;
    if (threadIdx.x == 0) mis = 0;
    __syncthreads();
    int any = 0;
    for (int i = threadIdx.x; i < 1024; i += 256)
      if ((i & 3) != 0 && mask_in[i] != 0) any = 1;
    if (any) atomicAdd(&mis, 1);
    __syncthreads();
    for (int i = threadIdx.x; i < 1024; i += 256) {
      if (mis == 0) mask_out[i] = (((const int*)mask_in)[i] != 0) ? 1 : 0;  // int32 storage
      else          mask_out[i] = mask_in[i] ? 1 : 0;                       // u8/bool storage
    }
    return;
  }
  const float* s; bfu* d; int n;
  switch (blockIdx.y) {
    case 0:  s = s0; d = d0; n = 4194304; break;
    case 1:  s = s1; d = d1; n = 4194304; break;
    case 2:  s = s2; d = d2; n = 1048576; break;
    default: s = s3; d = d3; n = 1048576; break;
  }
  for (int i = (blockIdx.x * 256 + threadIdx.x) * 8; i < n; i += 512 * 256 * 8) {
    float4 a = *(const float4*)(s + i);
    float4 b = *(const float4*)(s + i + 4);
    short8 pk;
    pk[0] = (short)f2bf(a.x); pk[1] = (short)f2bf(a.y);
    pk[2] = (short)f2bf(a.z); pk[3] = (short)f2bf(a.w);
    pk[4] = (short)f2bf(b.x); pk[5] = (short)f2bf(b.y);
    pk[6] = (short)f2bf(b.z); pk[7] = (short)f2bf(b.w);
    *(short8*)(d + i) = pk;
  }
}

// Fused Q/K/V projection: 64x128 tile, 8 waves (512 thr), wave = 16x64.
// grid (24,32) = 768 blocks = 3/CU, 24 waves/CU. Swizzled LDS, counted-vmcnt.
__global__ __launch_bounds__(512) void gemm_qkv(
    const bfu* __restrict__ A, const bfu* __restrict__ Bq,
    const bfu* __restrict__ Bk, const bfu* __restrict__ Bv,
    bfu* __restrict__ qr, bfu* __restrict__ kro, bfu* __restrict__ vt,
    const float* __restrict__ cosb, const float* __restrict__ sinb, float qsc) {
  __shared__ bfu As[2][64 * 64];    // 16 KB
  __shared__ bfu Bs[2][128 * 64];   // 32 KB
  const int bx = blockIdx.x;
  int path, n0;
  const bfu* B;
  if (bx < 16)      { path = 0; B = Bq; n0 = bx * 128; }
  else if (bx < 20) { path = 1; B = Bk; n0 = (bx - 16) * 128; }
  else              { path = 2; B = Bv; n0 = (bx - 20) * 128; }
  const int t = threadIdx.x;
  const int wid = t >> 6, lane = t & 63;
  const int wr = wid >> 1, wc = wid & 1;   // wave = rows wr*16.., cols wc*64..
  const int lr = lane & 15, lh = lane >> 4;
  const int m0 = blockIdx.y * 64;
  const int K = EE;
  f32x4 acc[4] = {};

  // A: chunk t (512 total); B: chunks t and t+512. 3 gload16 per thread.
  const int srow = t >> 3, sslot = t & 7;
  const int browB = (t + 512) >> 3, sslotB = (t + 512) & 7;
  auto stage = [&](int buf, int k0) {
    gload16(A + (size_t)(m0 + srow) * K + k0 + ((sslot ^ (srow & 7)) * 8),
            &As[buf][wid * 512]);
    gload16(B + (size_t)(n0 + srow) * K + k0 + ((sslot ^ (srow & 7)) * 8),
            &Bs[buf][wid * 512]);
    gload16(B + (size_t)(n0 + browB) * K + k0 + ((sslotB ^ (browB & 7)) * 8),
            &Bs[buf][4096 + wid * 512]);
  };

  stage(0, 0);
  for (int kt = 0; kt < 32; ++kt) {
    const int cur = kt & 1;
    if (kt < 31) {
      stage(cur ^ 1, (kt + 1) * 64);
      asm volatile("s_waitcnt vmcnt(3)" ::: "memory");  // cur tile's 3 loads done
    } else {
      asm volatile("s_waitcnt vmcnt(0)" ::: "memory");
    }
    GBAR();  // buf[cur] visible; prefetch stays in flight
    #pragma unroll
    for (int ks = 0; ks < 2; ++ks) {
      short8 a, b[4];
      a = *(const short8*)(&As[cur][(wr * 16 + lr) * 64 +
                                    (((ks * 4 + lh) ^ (lr & 7)) * 8)]);
      #pragma unroll
      for (int n = 0; n < 4; ++n)
        b[n] = *(const short8*)(&Bs[cur][(wc * 64 + n * 16 + lr) * 64 +
                                         (((ks * 4 + lh) ^ (lr & 7)) * 8)]);
      #pragma unroll
      for (int n = 0; n < 4; ++n)
        acc[n] = __builtin_amdgcn_mfma_f32_16x16x32_bf16(a, b[n], acc[n], 0, 0, 0);
    }
    GBAR();  // all waves done reading buf[cur]
  }
  #pragma unroll
  for (int r = 0; r < 4; ++r) {
    const int row = m0 + wr * 16 + lh * 4 + r;
    #pragma unroll
    for (int n = 0; n < 4; ++n) {
      const int col = n0 + wc * 64 + n * 16 + lr;
      float x = acc[n][r];
      if (path == 2) {
        vt[((size_t)(row >> 6) * 512 + col) * 64 + (row & 63)] = f2bf(x);
      } else {
        const int d = col & 63;
        float xp = (n < 2) ? -acc[n + 2][r] : acc[n - 2][r];
        float c = cosb[row * 64 + d], s = sinb[row * 64 + d];
        float sc = (path == 0) ? qsc : 1.0f;
        bfu* dst = (path == 0) ? qr : kro;
        dst[((size_t)(col >> 6) * TT + row) * 64 + d] = f2bf((x * c + xp * s) * sc);
      }
    }
  }
}

// O-projection: 64x128 tile, 8 waves, grid (16,32) = 512 blocks.
__global__ __launch_bounds__(512) void gemm_o(
    const bfu* __restrict__ A, const bfu* __restrict__ B,
    float* __restrict__ outF, int M, int N, int K) {
  __shared__ bfu As[2][64 * 64];
  __shared__ bfu Bs[2][128 * 64];
  const int t = threadIdx.x;
  const int wid = t >> 6, lane = t & 63;
  const int wr = wid >> 1, wc = wid & 1;
  const int lr = lane & 15, lh = lane >> 4;
  const int m0 = blockIdx.y * 64, n0 = blockIdx.x * 128;
  f32x4 acc[4] = {};

  const int srow = t >> 3, sslot = t & 7;
  const int browB = (t + 512) >> 3, sslotB = (t + 512) & 7;
  auto stage = [&](int buf, int k0) {
    gload16(A + (size_t)(m0 + srow) * K + k0 + ((sslot ^ (srow & 7)) * 8),
            &As[buf][wid * 512]);
    gload16(B + (size_t)(n0 + srow) * K + k0 + ((sslot ^ (srow & 7)) * 8),
            &Bs[buf][wid * 512]);
    gload16(B + (size_t)(n0 + browB) * K + k0 + ((sslotB ^ (browB & 7)) * 8),
            &Bs[buf][4096 + wid * 512]);
  };

  stage(0, 0);
  const int nk = K >> 6;
  for (int kt = 0; kt < nk; ++kt) {
    const int cur = kt & 1;
    if (kt < nk - 1) {
      stage(cur ^ 1, (kt + 1) * 64);
      asm volatile("s_waitcnt vmcnt(3)" ::: "memory");
    } else {
      asm volatile("s_waitcnt vmcnt(0)" ::: "memory");
    }
    GBAR();
    #pragma unroll
    for (int ks = 0; ks < 2; ++ks) {
      short8 a, b[4];
      a = *(const short8*)(&As[cur][(wr * 16 + lr) * 64 +
                                    (((ks * 4 + lh) ^ (lr & 7)) * 8)]);
      #pragma unroll
      for (int n = 0; n < 4; ++n)
        b[n] = *(const short8*)(&Bs[cur][(wc * 64 + n * 16 + lr) * 64 +
                                         (((ks * 4 + lh) ^ (lr & 7)) * 8)]);
      #pragma unroll
      for (int n = 0; n < 4; ++n)
        acc[n] = __builtin_amdgcn_mfma_f32_16x16x32_bf16(a, b[n], acc[n], 0, 0, 0);
    }
    GBAR();
  }
  #pragma unroll
  for (int r = 0; r < 4; ++r) {
    const int row = m0 + wr * 16 + lh * 4 + r;
    #pragma unroll
    for (int n = 0; n < 4; ++n)
      outF[(size_t)row * N + n0 + wc * 64 + n * 16 + lr] = acc[n][r];
  }
}

// Flash attention (R12-best structure): paired tiles, LDS-staged K/V with
// swizzle, swapped-QK in-lane softmax, raw v_exp, ones-MFMA denominator.
// blockIdx.y==32 blocks convert Wo f32->bf16 (overlapped with attention).
__global__ __launch_bounds__(256, 4) void attn_kernel(
    const bfu* __restrict__ qr, const bfu* __restrict__ kr,
    const bfu* __restrict__ vt, const unsigned char* __restrict__ allow,
    bfu* __restrict__ ao,
    const float* __restrict__ WoF, bfu* __restrict__ wob) {
  if (blockIdx.y == 32) {  // Wo conversion rider: 32 blocks x 256 thr
    for (int i = (blockIdx.x * 256 + threadIdx.x) * 8; i < 4194304; i += 32 * 256 * 8) {
      float4 a = *(const float4*)(WoF + i);
      float4 b = *(const float4*)(WoF + i + 4);
      short8 pk;
      pk[0] = (short)f2bf(a.x); pk[1] = (short)f2bf(a.y);
      pk[2] = (short)f2bf(a.z); pk[3] = (short)f2bf(a.w);
      pk[4] = (short)f2bf(b.x); pk[5] = (short)f2bf(b.y);
      pk[6] = (short)f2bf(b.z); pk[7] = (short)f2bf(b.w);
      *(short8*)(wob + i) = pk;
    }
    return;
  }
  const int qb = 31 - blockIdx.x;  // heavy q-blocks first
  const int h = blockIdx.y, kv = h >> 2;
  const int t = threadIdx.x, wid = t >> 6, lane = t & 63;
  const int lr = lane & 15, lh = lane >> 4;
  const int q0 = qb * 64;
  const int qrow = q0 + wid * 16 + lr;
  __shared__ bfu KB[2][64 * 64];
  __shared__ bfu VB[2][64 * 64];
  __shared__ bfu P[4][16 * 64];
  bfu* Pw = P[wid];

  unsigned int amask = 0, emask = 0;
  for (int kb = 0; kb < 32; ++kb) {
    bool bm = allow[qb * 32 + kb] != 0;
    bool fw = (kb < 4) || (kb >= qb - 3 && kb <= qb - 1);
    bool ed = (kb == qb) || (kb == qb - 4);
    if (bm || fw || ed) {
      amask |= 1u << kb;
      if (!bm && !fw) emask |= 1u << kb;
    }
  }

  short8 bq[2];
  #pragma unroll
  for (int ks = 0; ks < 2; ++ks)
    bq[ks] = *(const short8*)(qr + ((size_t)h * TT + qrow) * 64 + ks * 32 + lh * 8);

  short8 vones;
  #pragma unroll
  for (int i = 0; i < 8; ++i) vones[i] = (short)0x3F80;  // bf16 1.0

  f32x4 o[4] = {};
  f32x4 o_l = {};
  float m_reg = -1e30f;

  auto stage = [&](bfu* buf, const bfu* gbase) {
    #pragma unroll
    for (int c = 0; c < 2; ++c) {
      int chunk = wid * 128 + c * 64 + lane;
      int row = chunk >> 3, s = chunk & 7;
      gload16(gbase + row * 64 + (s ^ (row & 7)) * 8,
              buf + (wid * 128 + c * 64) * 8);
    }
  };

  auto qk_tile = [&](const bfu* KBuf, int kb, f32x4 s[4]) {
    __builtin_amdgcn_s_setprio(1);
    #pragma unroll
    for (int j = 0; j < 4; ++j) {
      const int row = j * 16 + lr;
      short8 a0 = *(const short8*)(KBuf + row * 64 + ((lh    ) ^ (row & 7)) * 8);
      short8 a1 = *(const short8*)(KBuf + row * 64 + ((lh + 4) ^ (row & 7)) * 8);
      f32x4 z = {};
      z = __builtin_amdgcn_mfma_f32_16x16x32_bf16(a0, bq[0], z, 0, 0, 0);
      s[j] = __builtin_amdgcn_mfma_f32_16x16x32_bf16(a1, bq[1], z, 0, 0, 0);
    }
    __builtin_amdgcn_s_setprio(0);
    if ((emask >> kb) & 1) {
      #pragma unroll
      for (int j = 0; j < 4; ++j)
        #pragma unroll
        for (int reg = 0; reg < 4; ++reg) {
          int k = kb * 64 + j * 16 + lh * 4 + reg;
          bool ok = (k <= qrow && k >= qrow - 255) || (k < 256);
          if (!ok) s[j][reg] = -1e30f;
        }
    }
  };

  auto pv_tile = [&](const bfu* VBuf, f32x4 s[4]) {
    #pragma unroll
    for (int j = 0; j < 4; ++j) {
      unsigned int w0 = cvtpk(s[j][0], s[j][1]);
      unsigned int w1 = cvtpk(s[j][2], s[j][3]);
      int base = lr * 64 + (((j * 2 + (lh >> 1)) ^ (lr & 7)) * 8) + (lh & 1) * 4;
      *(unsigned int*)(Pw + base) = w0;
      *(unsigned int*)(Pw + base + 2) = w1;
    }
    short8 pa[2];
    #pragma unroll
    for (int ks = 0; ks < 2; ++ks)
      pa[ks] = *(const short8*)(Pw + lr * 64 + (((ks * 4 + lh) ^ (lr & 7)) * 8));
    __builtin_amdgcn_s_setprio(1);
    #pragma unroll
    for (int n = 0; n < 4; ++n) {
      #pragma unroll
      for (int ks = 0; ks < 2; ++ks) {
        const int row = n * 16 + lr;
        short8 bv = *(const short8*)(VBuf + row * 64 + ((ks * 4 + lh) ^ (row & 7)) * 8);
        o[n] = __builtin_amdgcn_mfma_f32_16x16x32_bf16(pa[ks], bv, o[n], 0, 0, 0);
      }
    }
    o_l = __builtin_amdgcn_mfma_f32_16x16x32_bf16(pa[0], vones, o_l, 0, 0, 0);
    o_l = __builtin_amdgcn_mfma_f32_16x16x32_bf16(pa[1], vones, o_l, 0, 0, 0);
    __builtin_amdgcn_s_setprio(0);
  };

  unsigned int am = amask;
  while (am) {
    const int k1 = __ffs(am) - 1; am &= am - 1;
    int k2 = -1;
    if (am) { k2 = __ffs(am) - 1; am &= am - 1; }

    __syncthreads();
    stage(KB[0], kr + ((size_t)kv * TT + k1 * 64) * 64);
    stage(VB[0], vt + ((size_t)k1 * 512 + kv * 64) * 64);
    if (k2 >= 0) {
      stage(KB[1], kr + ((size_t)kv * TT + k2 * 64) * 64);
      stage(VB[1], vt + ((size_t)k2 * 512 + kv * 64) * 64);
    }
    __syncthreads();

    f32x4 s1[4], s2[4];
    qk_tile(KB[0], k1, s1);
    if (k2 >= 0) qk_tile(KB[1], k2, s2);

    float mx = fmaxf(fmaxf(s1[0][0], s1[0][1]), fmaxf(s1[0][2], s1[0][3]));
    #pragma unroll
    for (int j = 1; j < 4; ++j)
      mx = fmaxf(mx, fmaxf(fmaxf(s1[j][0], s1[j][1]), fmaxf(s1[j][2], s1[j][3])));
    if (k2 >= 0) {
      #pragma unroll
      for (int j = 0; j < 4; ++j)
        mx = fmaxf(mx, fmaxf(fmaxf(s2[j][0], s2[j][1]), fmaxf(s2[j][2], s2[j][3])));
    }
    mx = fmaxf(mx, __shfl_xor(mx, 16));
    mx = fmaxf(mx, __shfl_xor(mx, 32));

    if (__any(mx > m_reg)) {
      float mnew = fmaxf(m_reg, mx);
      float corr = fexp2(m_reg - mnew);
      m_reg = mnew;
      #pragma unroll
      for (int r = 0; r < 4; ++r) {
        float cr = __shfl(corr, lh * 4 + r);
        #pragma unroll
        for (int n = 0; n < 4; ++n) o[n][r] *= cr;
        o_l[r] *= cr;
      }
    }

    #pragma unroll
    for (int j = 0; j < 4; ++j)
      #pragma unroll
      for (int reg = 0; reg < 4; ++reg)
        s1[j][reg] = fexp2(s1[j][reg] - m_reg);
    if (k2 >= 0) {
      #pragma unroll
      for (int j = 0; j < 4; ++j)
        #pragma unroll
        for (int reg = 0; reg < 4; ++reg)
          s2[j][reg] = fexp2(s2[j][reg] - m_reg);
    }

    pv_tile(VB[0], s1);
    if (k2 >= 0) pv_tile(VB[1], s2);
  }

  #pragma unroll
  for (int r = 0; r < 4; ++r) {
    float inv = 1.0f / o_l[r];
    #pragma unroll
    for (int n = 0; n < 4; ++n) {
      float val = o[n][r] * inv;
      ao[(size_t)(q0 + wid * 16 + lh * 4 + r) * EE + h * 64 + n * 16 + lr] = f2bf(val);
    }
  }
}

extern "C" void kernel_launch(void* const* d_in, const int* in_sizes, int n_in,
                              void* d_out, int out_size, void* d_ws, size_t ws_size,
                              hipStream_t stream) {
  const float* hs   = (const float*)d_in[0];
  const float* cosb = (const float*)d_in[1];
  const float* sinb = (const float*)d_in[2];
  const float* Wq   = (const float*)d_in[3];
  const float* Wk   = (const float*)d_in[4];
  const float* Wv   = (const float*)d_in[5];
  const float* Wo   = (const float*)d_in[6];
  const unsigned char* allow_raw = (const unsigned char*)d_in[7];
  float* out = (float*)d_out;

  char* ws = (char*)d_ws;
  const size_t MB = 1024 * 1024;
  bfu* hsb = (bfu*)(ws);            // [2048][2048] 8 MB (reused as ao later)
  bfu* wqb = (bfu*)(ws + 8 * MB);   // 8 MB
  bfu* wkb = (bfu*)(ws + 16 * MB);  // 2 MB
  bfu* wvb = (bfu*)(ws + 18 * MB);  // 2 MB
  bfu* wob = (bfu*)(ws + 20 * MB);  // 8 MB
  bfu* qr  = (bfu*)(ws + 28 * MB);  // [32][2048][64] 8 MB
  bfu* kr  = (bfu*)(ws + 36 * MB);  // [8][2048][64]  2 MB
  bfu* vt  = (bfu*)(ws + 38 * MB);  // [32][512][64]  2 MB (tile-major)
  unsigned char* maskc = (unsigned char*)(ws + 40 * MB);  // 1 KB
  bfu* ao = hsb;

  cvt5<<<dim3(512, 5), 256, 0, stream>>>(hs, Wq, Wk, Wv,
                                         hsb, wqb, wkb, wvb,
                                         allow_raw, maskc);

  const float QSC = 0.125f * 1.44269504088896f;  // head scale * log2(e)
  gemm_qkv<<<dim3(24, 32), 512, 0, stream>>>(
      hsb, wqb, wkb, wvb, qr, kr, vt, cosb, sinb, QSC);

  attn_kernel<<<dim3(32, 33), 256, 0, stream>>>(qr, kr, vt, maskc, ao, Wo, wob);

  gemm_o<<<dim3(16, 32), 512, 0, stream>>>(ao, wob, out, 2048, 2048, 2048);
}

// Round 17
// 121.155 us; speedup vs baseline: 1.7099x; 1.0656x over previous
//
#include <hip/hip_runtime.h>

typedef unsigned short bfu;
typedef __attribute__((ext_vector_type(8))) short short8;
typedef __attribute__((ext_vector_type(4))) float f32x4;

#define TT 2048
#define EE 2048

// Raw barrier without the vmcnt(0) drain __syncthreads would emit.
#define GBAR() do { __builtin_amdgcn_sched_barrier(0); \
                    __builtin_amdgcn_s_barrier();      \
                    __builtin_amdgcn_sched_barrier(0); } while (0)

__device__ __forceinline__ unsigned short f2bf(float f) {
  union { float fv; unsigned int u; } v; v.fv = f;
  unsigned int r = v.u + 0x7fffu + ((v.u >> 16) & 1u);
  return (unsigned short)(r >> 16);
}

// Native packed f32->bf16 (RNE): D.lo = bf16(lo), D.hi = bf16(hi).
__device__ __forceinline__ unsigned int cvtpk(float lo, float hi) {
  unsigned int r;
  asm("v_cvt_pk_bf16_f32 %0, %1, %2" : "=v"(r) : "v"(lo), "v"(hi));
  return r;
}

// Single-instruction exp2 (v_exp_f32 IS 2^x); x <= 0 here, -1e30 -> 0.
__device__ __forceinline__ float fexp2(float x) {
  float r;
  asm("v_exp_f32 %0, %1" : "=v"(r) : "v"(x));
  return r;
}

__device__ __forceinline__ void gload16(const void* g, void* l) {
  __builtin_amdgcn_global_load_lds(
      (const __attribute__((address_space(1))) unsigned int*)g,
      (__attribute__((address_space(3))) unsigned int*)l, 16, 0, 0);
}

// Fused f32->bf16 conversion (y<5) + block-mask canonicalization (y==5).
// grid (1024, 6).
__global__ __launch_bounds__(256) void cvt5(
    const float* __restrict__ s0, const float* __restrict__ s1,
    const float* __restrict__ s2, const float* __restrict__ s3,
    const float* __restrict__ s4,
    bfu* __restrict__ d0, bfu* __restrict__ d1, bfu* __restrict__ d2,
    bfu* __restrict__ d3, bfu* __restrict__ d4,
    const unsigned char* __restrict__ mask_in, unsigned char* __restrict__ mask_out) {
  if (blockIdx.y == 5) {
    if (blockIdx.x != 0) return;
    __shared__ int mis;
    if (threadIdx.x == 0) mis = 0;
    __syncthreads();
    int any = 0;
    for (int i = threadIdx.x; i < 1024; i += 256)
      if ((i & 3) != 0 && mask_in[i] != 0) any = 1;
    if (any) atomicAdd(&mis, 1);
    __syncthreads();
    for (int i = threadIdx.x; i < 1024; i += 256) {
      if (mis == 0) mask_out[i] = (((const int*)mask_in)[i] != 0) ? 1 : 0;  // int32 storage
      else          mask_out[i] = mask_in[i] ? 1 : 0;                       // u8/bool storage
    }
    return;
  }
  const float* s; bfu* d; int n;
  switch (blockIdx.y) {
    case 0:  s = s0; d = d0; n = 4194304; break;
    case 1:  s = s1; d = d1; n = 4194304; break;
    case 2:  s = s2; d = d2; n = 1048576; break;
    case 3:  s = s3; d = d3; n = 1048576; break;
    default: s = s4; d = d4; n = 4194304; break;
  }
  for (int i = (blockIdx.x * 256 + threadIdx.x) * 8; i < n; i += 1024 * 256 * 8) {
    float4 a = *(const float4*)(s + i);
    float4 b = *(const float4*)(s + i + 4);
    short8 pk;
    pk[0] = (short)f2bf(a.x); pk[1] = (short)f2bf(a.y);
    pk[2] = (short)f2bf(a.z); pk[3] = (short)f2bf(a.w);
    pk[4] = (short)f2bf(b.x); pk[5] = (short)f2bf(b.y);
    pk[6] = (short)f2bf(b.z); pk[7] = (short)f2bf(b.w);
    *(short8*)(d + i) = pk;
  }
}

// Fused Q/K/V projection: 64x128 tile, 8 waves (512 thr), wave = 16x64.
// grid (24,32) = 768 blocks = 3/CU, 24 waves/CU. Swizzled LDS, counted-vmcnt.
__global__ __launch_bounds__(512) void gemm_qkv(
    const bfu* __restrict__ A, const bfu* __restrict__ Bq,
    const bfu* __restrict__ Bk, const bfu* __restrict__ Bv,
    bfu* __restrict__ qr, bfu* __restrict__ kro, bfu* __restrict__ vt,
    const float* __restrict__ cosb, const float* __restrict__ sinb, float qsc) {
  __shared__ bfu As[2][64 * 64];    // 16 KB
  __shared__ bfu Bs[2][128 * 64];   // 32 KB
  const int bx = blockIdx.x;
  int path, n0;
  const bfu* B;
  if (bx < 16)      { path = 0; B = Bq; n0 = bx * 128; }
  else if (bx < 20) { path = 1; B = Bk; n0 = (bx - 16) * 128; }
  else              { path = 2; B = Bv; n0 = (bx - 20) * 128; }
  const int t = threadIdx.x;
  const int wid = t >> 6, lane = t & 63;
  const int wr = wid >> 1, wc = wid & 1;   // wave = rows wr*16.., cols wc*64..
  const int lr = lane & 15, lh = lane >> 4;
  const int m0 = blockIdx.y * 64;
  const int K = EE;
  f32x4 acc[4] = {};

  // A: chunk t (512 total); B: chunks t and t+512. 3 gload16 per thread.
  const int srow = t >> 3, sslot = t & 7;
  const int browB = (t + 512) >> 3, sslotB = (t + 512) & 7;
  auto stage = [&](int buf, int k0) {
    gload16(A + (size_t)(m0 + srow) * K + k0 + ((sslot ^ (srow & 7)) * 8),
            &As[buf][wid * 512]);
    gload16(B + (size_t)(n0 + srow) * K + k0 + ((sslot ^ (srow & 7)) * 8),
            &Bs[buf][wid * 512]);
    gload16(B + (size_t)(n0 + browB) * K + k0 + ((sslotB ^ (browB & 7)) * 8),
            &Bs[buf][4096 + wid * 512]);
  };

  stage(0, 0);
  for (int kt = 0; kt < 32; ++kt) {
    const int cur = kt & 1;
    if (kt < 31) {
      stage(cur ^ 1, (kt + 1) * 64);
      asm volatile("s_waitcnt vmcnt(3)" ::: "memory");  // cur tile's 3 loads done
    } else {
      asm volatile("s_waitcnt vmcnt(0)" ::: "memory");
    }
    GBAR();  // buf[cur] visible; prefetch stays in flight
    #pragma unroll
    for (int ks = 0; ks < 2; ++ks) {
      short8 a, b[4];
      a = *(const short8*)(&As[cur][(wr * 16 + lr) * 64 +
                                    (((ks * 4 + lh) ^ (lr & 7)) * 8)]);
      #pragma unroll
      for (int n = 0; n < 4; ++n)
        b[n] = *(const short8*)(&Bs[cur][(wc * 64 + n * 16 + lr) * 64 +
                                         (((ks * 4 + lh) ^ (lr & 7)) * 8)]);
      #pragma unroll
      for (int n = 0; n < 4; ++n)
        acc[n] = __builtin_amdgcn_mfma_f32_16x16x32_bf16(a, b[n], acc[n], 0, 0, 0);
    }
    GBAR();  // all waves done reading buf[cur]
  }
  #pragma unroll
  for (int r = 0; r < 4; ++r) {
    const int row = m0 + wr * 16 + lh * 4 + r;
    #pragma unroll
    for (int n = 0; n < 4; ++n) {
      const int col = n0 + wc * 64 + n * 16 + lr;
      float x = acc[n][r];
      if (path == 2) {
        vt[((size_t)(row >> 6) * 512 + col) * 64 + (row & 63)] = f2bf(x);
      } else {
        const int d = col & 63;
        float xp = (n < 2) ? -acc[n + 2][r] : acc[n - 2][r];
        float c = cosb[row * 64 + d], s = sinb[row * 64 + d];
        float sc = (path == 0) ? qsc : 1.0f;
        bfu* dst = (path == 0) ? qr : kro;
        dst[((size_t)(col >> 6) * TT + row) * 64 + d] = f2bf((x * c + xp * s) * sc);
      }
    }
  }
}

// O-projection: 64x128 tile, 8 waves, grid (16,32) = 512 blocks.
__global__ __launch_bounds__(512) void gemm_o(
    const bfu* __restrict__ A, const bfu* __restrict__ B,
    float* __restrict__ outF, int M, int N, int K) {
  __shared__ bfu As[2][64 * 64];
  __shared__ bfu Bs[2][128 * 64];
  const int t = threadIdx.x;
  const int wid = t >> 6, lane = t & 63;
  const int wr = wid >> 1, wc = wid & 1;
  const int lr = lane & 15, lh = lane >> 4;
  const int m0 = blockIdx.y * 64, n0 = blockIdx.x * 128;
  f32x4 acc[4] = {};

  const int srow = t >> 3, sslot = t & 7;
  const int browB = (t + 512) >> 3, sslotB = (t + 512) & 7;
  auto stage = [&](int buf, int k0) {
    gload16(A + (size_t)(m0 + srow) * K + k0 + ((sslot ^ (srow & 7)) * 8),
            &As[buf][wid * 512]);
    gload16(B + (size_t)(n0 + srow) * K + k0 + ((sslot ^ (srow & 7)) * 8),
            &Bs[buf][wid * 512]);
    gload16(B + (size_t)(n0 + browB) * K + k0 + ((sslotB ^ (browB & 7)) * 8),
            &Bs[buf][4096 + wid * 512]);
  };

  stage(0, 0);
  const int nk = K >> 6;
  for (int kt = 0; kt < nk; ++kt) {
    const int cur = kt & 1;
    if (kt < nk - 1) {
      stage(cur ^ 1, (kt + 1) * 64);
      asm volatile("s_waitcnt vmcnt(3)" ::: "memory");
    } else {
      asm volatile("s_waitcnt vmcnt(0)" ::: "memory");
    }
    GBAR();
    #pragma unroll
    for (int ks = 0; ks < 2; ++ks) {
      short8 a, b[4];
      a = *(const short8*)(&As[cur][(wr * 16 + lr) * 64 +
                                    (((ks * 4 + lh) ^ (lr & 7)) * 8)]);
      #pragma unroll
      for (int n = 0; n < 4; ++n)
        b[n] = *(const short8*)(&Bs[cur][(wc * 64 + n * 16 + lr) * 64 +
                                         (((ks * 4 + lh) ^ (lr & 7)) * 8)]);
      #pragma unroll
      for (int n = 0; n < 4; ++n)
        acc[n] = __builtin_amdgcn_mfma_f32_16x16x32_bf16(a, b[n], acc[n], 0, 0, 0);
    }
    GBAR();
  }
  #pragma unroll
  for (int r = 0; r < 4; ++r) {
    const int row = m0 + wr * 16 + lh * 4 + r;
    #pragma unroll
    for (int n = 0; n < 4; ++n)
      outF[(size_t)row * N + n0 + wc * 64 + n * 16 + lr] = acc[n][r];
  }
}

// Flash attention (R12-best): paired tiles, LDS-staged K/V with swizzle,
// swapped-QK in-lane softmax, raw v_exp, ones-MFMA denominator.
// Heavy q-blocks dispatch first (qb = 31 - bx).
__global__ __launch_bounds__(256, 4) void attn_kernel(
    const bfu* __restrict__ qr, const bfu* __restrict__ kr,
    const bfu* __restrict__ vt, const unsigned char* __restrict__ allow,
    bfu* __restrict__ ao) {
  const int qb = 31 - blockIdx.x;
  const int h = blockIdx.y, kv = h >> 2;
  const int t = threadIdx.x, wid = t >> 6, lane = t & 63;
  const int lr = lane & 15, lh = lane >> 4;
  const int q0 = qb * 64;
  const int qrow = q0 + wid * 16 + lr;
  __shared__ bfu KB[2][64 * 64];
  __shared__ bfu VB[2][64 * 64];
  __shared__ bfu P[4][16 * 64];
  bfu* Pw = P[wid];

  unsigned int amask = 0, emask = 0;
  for (int kb = 0; kb < 32; ++kb) {
    bool bm = allow[qb * 32 + kb] != 0;
    bool fw = (kb < 4) || (kb >= qb - 3 && kb <= qb - 1);
    bool ed = (kb == qb) || (kb == qb - 4);
    if (bm || fw || ed) {
      amask |= 1u << kb;
      if (!bm && !fw) emask |= 1u << kb;
    }
  }

  short8 bq[2];
  #pragma unroll
  for (int ks = 0; ks < 2; ++ks)
    bq[ks] = *(const short8*)(qr + ((size_t)h * TT + qrow) * 64 + ks * 32 + lh * 8);

  short8 vones;
  #pragma unroll
  for (int i = 0; i < 8; ++i) vones[i] = (short)0x3F80;  // bf16 1.0

  f32x4 o[4] = {};
  f32x4 o_l = {};
  float m_reg = -1e30f;

  auto stage = [&](bfu* buf, const bfu* gbase) {
    #pragma unroll
    for (int c = 0; c < 2; ++c) {
      int chunk = wid * 128 + c * 64 + lane;
      int row = chunk >> 3, s = chunk & 7;
      gload16(gbase + row * 64 + (s ^ (row & 7)) * 8,
              buf + (wid * 128 + c * 64) * 8);
    }
  };

  auto qk_tile = [&](const bfu* KBuf, int kb, f32x4 s[4]) {
    __builtin_amdgcn_s_setprio(1);
    #pragma unroll
    for (int j = 0; j < 4; ++j) {
      const int row = j * 16 + lr;
      short8 a0 = *(const short8*)(KBuf + row * 64 + ((lh    ) ^ (row & 7)) * 8);
      short8 a1 = *(const short8*)(KBuf + row * 64 + ((lh + 4) ^ (row & 7)) * 8);
      f32x4 z = {};
      z = __builtin_amdgcn_mfma_f32_16x16x32_bf16(a0, bq[0], z, 0, 0, 0);
      s[j] = __builtin_amdgcn_mfma_f32_16x16x32_bf16(a1, bq[1], z, 0, 0, 0);
    }
    __builtin_amdgcn_s_setprio(0);
    if ((emask >> kb) & 1) {
      #pragma unroll
      for (int j = 0; j < 4; ++j)
        #pragma unroll
        for (int reg = 0; reg < 4; ++reg) {
          int k = kb * 64 + j * 16 + lh * 4 + reg;
          bool ok = (k <= qrow && k >= qrow - 255) || (k < 256);
          if (!ok) s[j][reg] = -1e30f;
        }
    }
  };

  auto pv_tile = [&](const bfu* VBuf, f32x4 s[4]) {
    #pragma unroll
    for (int j = 0; j < 4; ++j) {
      unsigned int w0 = cvtpk(s[j][0], s[j][1]);
      unsigned int w1 = cvtpk(s[j][2], s[j][3]);
      int base = lr * 64 + (((j * 2 + (lh >> 1)) ^ (lr & 7)) * 8) + (lh & 1) * 4;
      *(unsigned int*)(Pw + base) = w0;
      *(unsigned int*)(Pw + base + 2) = w1;
    }
    short8 pa[2];
    #pragma unroll
    for (int ks = 0; ks < 2; ++ks)
      pa[ks] = *(const short8*)(Pw + lr * 64 + (((ks * 4 + lh) ^ (lr & 7)) * 8));
    __builtin_amdgcn_s_setprio(1);
    #pragma unroll
    for (int n = 0; n < 4; ++n) {
      #pragma unroll
      for (int ks = 0; ks < 2; ++ks) {
        const int row = n * 16 + lr;
        short8 bv = *(const short8*)(VBuf + row * 64 + ((ks * 4 + lh) ^ (row & 7)) * 8);
        o[n] = __builtin_amdgcn_mfma_f32_16x16x32_bf16(pa[ks], bv, o[n], 0, 0, 0);
      }
    }
    o_l = __builtin_amdgcn_mfma_f32_16x16x32_bf16(pa[0], vones, o_l, 0, 0, 0);
    o_l = __builtin_amdgcn_mfma_f32_16x16x32_bf16(pa[1], vones, o_l, 0, 0, 0);
    __builtin_amdgcn_s_setprio(0);
  };

  unsigned int am = amask;
  while (am) {
    const int k1 = __ffs(am) - 1; am &= am - 1;
    int k2 = -1;
    if (am) { k2 = __ffs(am) - 1; am &= am - 1; }

    __syncthreads();
    stage(KB[0], kr + ((size_t)kv * TT + k1 * 64) * 64);
    stage(VB[0], vt + ((size_t)k1 * 512 + kv * 64) * 64);
    if (k2 >= 0) {
      stage(KB[1], kr + ((size_t)kv * TT + k2 * 64) * 64);
      stage(VB[1], vt + ((size_t)k2 * 512 + kv * 64) * 64);
    }
    __syncthreads();

    f32x4 s1[4], s2[4];
    qk_tile(KB[0], k1, s1);
    if (k2 >= 0) qk_tile(KB[1], k2, s2);

    float mx = fmaxf(fmaxf(s1[0][0], s1[0][1]), fmaxf(s1[0][2], s1[0][3]));
    #pragma unroll
    for (int j = 1; j < 4; ++j)
      mx = fmaxf(mx, fmaxf(fmaxf(s1[j][0], s1[j][1]), fmaxf(s1[j][2], s1[j][3])));
    if (k2 >= 0) {
      #pragma unroll
      for (int j = 0; j < 4; ++j)
        mx = fmaxf(mx, fmaxf(fmaxf(s2[j][0], s2[j][1]), fmaxf(s2[j][2], s2[j][3])));
    }
    mx = fmaxf(mx, __shfl_xor(mx, 16));
    mx = fmaxf(mx, __shfl_xor(mx, 32));

    if (__any(mx > m_reg)) {
      float mnew = fmaxf(m_reg, mx);
      float corr = fexp2(m_reg - mnew);
      m_reg = mnew;
      #pragma unroll
      for (int r = 0; r < 4; ++r) {
        float cr = __shfl(corr, lh * 4 + r);
        #pragma unroll
        for (int n = 0; n < 4; ++n) o[n][r] *= cr;
        o_l[r] *= cr;
      }
    }

    #pragma unroll
    for (int j = 0; j < 4; ++j)
      #pragma unroll
      for (int reg = 0; reg < 4; ++reg)
        s1[j][reg] = fexp2(s1[j][reg] - m_reg);
    if (k2 >= 0) {
      #pragma unroll
      for (int j = 0; j < 4; ++j)
        #pragma unroll
        for (int reg = 0; reg < 4; ++reg)
          s2[j][reg] = fexp2(s2[j][reg] - m_reg);
    }

    pv_tile(VB[0], s1);
    if (k2 >= 0) pv_tile(VB[1], s2);
  }

  #pragma unroll
  for (int r = 0; r < 4; ++r) {
    float inv = 1.0f / o_l[r];
    #pragma unroll
    for (int n = 0; n < 4; ++n) {
      float val = o[n][r] * inv;
      ao[(size_t)(q0 + wid * 16 + lh * 4 + r) * EE + h * 64 + n * 16 + lr] = f2bf(val);
    }
  }
}

extern "C" void kernel_launch(void* const* d_in, const int* in_sizes, int n_in,
                              void* d_out, int out_size, void* d_ws, size_t ws_size,
                              hipStream_t stream) {
  const float* hs   = (const float*)d_in[0];
  const float* cosb = (const float*)d_in[1];
  const float* sinb = (const float*)d_in[2];
  const float* Wq   = (const float*)d_in[3];
  const float* Wk   = (const float*)d_in[4];
  const float* Wv   = (const float*)d_in[5];
  const float* Wo   = (const float*)d_in[6];
  const unsigned char* allow_raw = (const unsigned char*)d_in[7];
  float* out = (float*)d_out;

  char* ws = (char*)d_ws;
  const size_t MB = 1024 * 1024;
  bfu* hsb = (bfu*)(ws);            // [2048][2048] 8 MB (reused as ao later)
  bfu* wqb = (bfu*)(ws + 8 * MB);   // 8 MB
  bfu* wkb = (bfu*)(ws + 16 * MB);  // 2 MB
  bfu* wvb = (bfu*)(ws + 18 * MB);  // 2 MB
  bfu* wob = (bfu*)(ws + 20 * MB);  // 8 MB
  bfu* qr  = (bfu*)(ws + 28 * MB);  // [32][2048][64] 8 MB
  bfu* kr  = (bfu*)(ws + 36 * MB);  // [8][2048][64]  2 MB
  bfu* vt  = (bfu*)(ws + 38 * MB);  // [32][512][64]  2 MB (tile-major)
  unsigned char* maskc = (unsigned char*)(ws + 40 * MB);  // 1 KB
  bfu* ao = hsb;

  cvt5<<<dim3(1024, 6), 256, 0, stream>>>(hs, Wq, Wk, Wv, Wo,
                                          hsb, wqb, wkb, wvb, wob,
                                          allow_raw, maskc);

  const float QSC = 0.125f * 1.44269504088896f;  // head scale * log2(e)
  gemm_qkv<<<dim3(24, 32), 512, 0, stream>>>(
      hsb, wqb, wkb, wvb, qr, kr, vt, cosb, sinb, QSC);

  attn_kernel<<<dim3(32, 32), 256, 0, stream>>>(qr, kr, vt, maskc, ao);

  gemm_o<<<dim3(16, 32), 512, 0, stream>>>(ao, wob, out, 2048, 2048, 2048);
}

// Round 18
// 119.546 us; speedup vs baseline: 1.7329x; 1.0135x over previous
//
#include <hip/hip_runtime.h>

typedef unsigned short bfu;
typedef __attribute__((ext_vector_type(8))) short short8;
typedef __attribute__((ext_vector_type(4))) float f32x4;

#define TT 2048
#define EE 2048

// Raw barrier without the vmcnt(0) drain __syncthreads would emit.
#define GBAR() do { __builtin_amdgcn_sched_barrier(0); \
                    __builtin_amdgcn_s_barrier();      \
                    __builtin_amdgcn_sched_barrier(0); } while (0)

__device__ __forceinline__ unsigned short f2bf(float f) {
  union { float fv; unsigned int u; } v; v.fv = f;
  unsigned int r = v.u + 0x7fffu + ((v.u >> 16) & 1u);
  return (unsigned short)(r >> 16);
}

// Native packed f32->bf16 (RNE): D.lo = bf16(lo), D.hi = bf16(hi).
__device__ __forceinline__ unsigned int cvtpk(float lo, float hi) {
  unsigned int r;
  asm("v_cvt_pk_bf16_f32 %0, %1, %2" : "=v"(r) : "v"(lo), "v"(hi));
  return r;
}

// Single-instruction exp2 (v_exp_f32 IS 2^x); -1e30 -> 0.
__device__ __forceinline__ float fexp2(float x) {
  float r;
  asm("v_exp_f32 %0, %1" : "=v"(r) : "v"(x));
  return r;
}

__device__ __forceinline__ void gload16(const void* g, void* l) {
  __builtin_amdgcn_global_load_lds(
      (const __attribute__((address_space(1))) unsigned int*)g,
      (__attribute__((address_space(3))) unsigned int*)l, 16, 0, 0);
}

// Fused f32->bf16 conversion (y<4: hs,Wq,Wk,Wv) + mask canon (y==4).
// Wo conversion is spread across gemm_qkv's 768 blocks (HBM idle there).
__global__ __launch_bounds__(256) void cvt5(
    const float* __restrict__ s0, const float* __restrict__ s1,
    const float* __restrict__ s2, const float* __restrict__ s3,
    bfu* __restrict__ d0, bfu* __restrict__ d1, bfu* __restrict__ d2,
    bfu* __restrict__ d3,
    const unsigned char* __restrict__ mask_in, unsigned char* __restrict__ mask_out) {
  if (blockIdx.y == 4) {
    if (blockIdx.x != 0) return;
    __shared__ int mis;
    if (threadIdx.x == 0) mis = 0;
    __syncthreads();
    int any = 0;
    for (int i = threadIdx.x; i < 1024; i += 256)
      if ((i & 3) != 0 && mask_in[i] != 0) any = 1;
    if (any) atomicAdd(&mis, 1);
    __syncthreads();
    for (int i = threadIdx.x; i < 1024; i += 256) {
      if (mis == 0) mask_out[i] = (((const int*)mask_in)[i] != 0) ? 1 : 0;  // int32 storage
      else          mask_out[i] = mask_in[i] ? 1 : 0;                       // u8/bool storage
    }
    return;
  }
  const float* s; bfu* d; int n;
  switch (blockIdx.y) {
    case 0:  s = s0; d = d0; n = 4194304; break;
    case 1:  s = s1; d = d1; n = 4194304; break;
    case 2:  s = s2; d = d2; n = 1048576; break;
    default: s = s3; d = d3; n = 1048576; break;
  }
  for (int i = (blockIdx.x * 256 + threadIdx.x) * 8; i < n; i += 1024 * 256 * 8) {
    float4 a = *(const float4*)(s + i);
    float4 b = *(const float4*)(s + i + 4);
    short8 pk;
    pk[0] = (short)f2bf(a.x); pk[1] = (short)f2bf(a.y);
    pk[2] = (short)f2bf(a.z); pk[3] = (short)f2bf(a.w);
    pk[4] = (short)f2bf(b.x); pk[5] = (short)f2bf(b.y);
    pk[6] = (short)f2bf(b.z); pk[7] = (short)f2bf(b.w);
    *(short8*)(d + i) = pk;
  }
}

// Fused Q/K/V projection: 64x128 tile, 8 waves (512 thr), wave = 16x64.
// grid (24,32) = 768 blocks = 3/CU, 24 waves/CU. Swizzled LDS, counted-vmcnt.
// Prologue: each block converts its grid-strided slice of Wo f32->bf16
// (24 MB rides free under the compute-bound loop's idle HBM).
__global__ __launch_bounds__(512) void gemm_qkv(
    const bfu* __restrict__ A, const bfu* __restrict__ Bq,
    const bfu* __restrict__ Bk, const bfu* __restrict__ Bv,
    bfu* __restrict__ qr, bfu* __restrict__ kro, bfu* __restrict__ vt,
    const float* __restrict__ cosb, const float* __restrict__ sinb, float qsc,
    const float* __restrict__ WoF, bfu* __restrict__ wob) {
  __shared__ bfu As[2][64 * 64];    // 16 KB
  __shared__ bfu Bs[2][128 * 64];   // 32 KB
  const int bx = blockIdx.x;
  int path, n0;
  const bfu* B;
  if (bx < 16)      { path = 0; B = Bq; n0 = bx * 128; }
  else if (bx < 20) { path = 1; B = Bk; n0 = (bx - 16) * 128; }
  else              { path = 2; B = Bv; n0 = (bx - 20) * 128; }
  const int t = threadIdx.x;

  // Wo conversion rider: grid-strided over all 768 blocks, then full drain
  // so the main loop's counted vmcnt stays exact (stores count in vmcnt).
  {
    const int bid = blockIdx.y * 24 + bx;
    for (int i = (bid * 512 + t) * 8; i < 4194304; i += 768 * 512 * 8) {
      float4 a = *(const float4*)(WoF + i);
      float4 b = *(const float4*)(WoF + i + 4);
      short8 pk;
      pk[0] = (short)f2bf(a.x); pk[1] = (short)f2bf(a.y);
      pk[2] = (short)f2bf(a.z); pk[3] = (short)f2bf(a.w);
      pk[4] = (short)f2bf(b.x); pk[5] = (short)f2bf(b.y);
      pk[6] = (short)f2bf(b.z); pk[7] = (short)f2bf(b.w);
      *(short8*)(wob + i) = pk;
    }
    asm volatile("s_waitcnt vmcnt(0)" ::: "memory");
  }

  const int wid = t >> 6, lane = t & 63;
  const int wr = wid >> 1, wc = wid & 1;   // wave = rows wr*16.., cols wc*64..
  const int lr = lane & 15, lh = lane >> 4;
  const int m0 = blockIdx.y * 64;
  const int K = EE;
  f32x4 acc[4] = {};

  // A: chunk t (512 total); B: chunks t and t+512. 3 gload16 per thread.
  const int srow = t >> 3, sslot = t & 7;
  const int browB = (t + 512) >> 3, sslotB = (t + 512) & 7;
  auto stage = [&](int buf, int k0) {
    gload16(A + (size_t)(m0 + srow) * K + k0 + ((sslot ^ (srow & 7)) * 8),
            &As[buf][wid * 512]);
    gload16(B + (size_t)(n0 + srow) * K + k0 + ((sslot ^ (srow & 7)) * 8),
            &Bs[buf][wid * 512]);
    gload16(B + (size_t)(n0 + browB) * K + k0 + ((sslotB ^ (browB & 7)) * 8),
            &Bs[buf][4096 + wid * 512]);
  };

  stage(0, 0);
  for (int kt = 0; kt < 32; ++kt) {
    const int cur = kt & 1;
    if (kt < 31) {
      stage(cur ^ 1, (kt + 1) * 64);
      asm volatile("s_waitcnt vmcnt(3)" ::: "memory");  // cur tile's 3 loads done
    } else {
      asm volatile("s_waitcnt vmcnt(0)" ::: "memory");
    }
    GBAR();  // buf[cur] visible; prefetch stays in flight
    #pragma unroll
    for (int ks = 0; ks < 2; ++ks) {
      short8 a, b[4];
      a = *(const short8*)(&As[cur][(wr * 16 + lr) * 64 +
                                    (((ks * 4 + lh) ^ (lr & 7)) * 8)]);
      #pragma unroll
      for (int n = 0; n < 4; ++n)
        b[n] = *(const short8*)(&Bs[cur][(wc * 64 + n * 16 + lr) * 64 +
                                         (((ks * 4 + lh) ^ (lr & 7)) * 8)]);
      #pragma unroll
      for (int n = 0; n < 4; ++n)
        acc[n] = __builtin_amdgcn_mfma_f32_16x16x32_bf16(a, b[n], acc[n], 0, 0, 0);
    }
    GBAR();  // all waves done reading buf[cur]
  }
  #pragma unroll
  for (int r = 0; r < 4; ++r) {
    const int row = m0 + wr * 16 + lh * 4 + r;
    #pragma unroll
    for (int n = 0; n < 4; ++n) {
      const int col = n0 + wc * 64 + n * 16 + lr;
      float x = acc[n][r];
      if (path == 2) {
        vt[((size_t)(row >> 6) * 512 + col) * 64 + (row & 63)] = f2bf(x);
      } else {
        const int d = col & 63;
        float xp = (n < 2) ? -acc[n + 2][r] : acc[n - 2][r];
        float c = cosb[row * 64 + d], s = sinb[row * 64 + d];
        float sc = (path == 0) ? qsc : 1.0f;
        bfu* dst = (path == 0) ? qr : kro;
        dst[((size_t)(col >> 6) * TT + row) * 64 + d] = f2bf((x * c + xp * s) * sc);
      }
    }
  }
}

// O-projection: 64x128 tile, 8 waves, grid (16,32) = 512 blocks.
__global__ __launch_bounds__(512) void gemm_o(
    const bfu* __restrict__ A, const bfu* __restrict__ B,
    float* __restrict__ outF, int M, int N, int K) {
  __shared__ bfu As[2][64 * 64];
  __shared__ bfu Bs[2][128 * 64];
  const int t = threadIdx.x;
  const int wid = t >> 6, lane = t & 63;
  const int wr = wid >> 1, wc = wid & 1;
  const int lr = lane & 15, lh = lane >> 4;
  const int m0 = blockIdx.y * 64, n0 = blockIdx.x * 128;
  f32x4 acc[4] = {};

  const int srow = t >> 3, sslot = t & 7;
  const int browB = (t + 512) >> 3, sslotB = (t + 512) & 7;
  auto stage = [&](int buf, int k0) {
    gload16(A + (size_t)(m0 + srow) * K + k0 + ((sslot ^ (srow & 7)) * 8),
            &As[buf][wid * 512]);
    gload16(B + (size_t)(n0 + srow) * K + k0 + ((sslot ^ (srow & 7)) * 8),
            &Bs[buf][wid * 512]);
    gload16(B + (size_t)(n0 + browB) * K + k0 + ((sslotB ^ (browB & 7)) * 8),
            &Bs[buf][4096 + wid * 512]);
  };

  stage(0, 0);
  const int nk = K >> 6;
  for (int kt = 0; kt < nk; ++kt) {
    const int cur = kt & 1;
    if (kt < nk - 1) {
      stage(cur ^ 1, (kt + 1) * 64);
      asm volatile("s_waitcnt vmcnt(3)" ::: "memory");
    } else {
      asm volatile("s_waitcnt vmcnt(0)" ::: "memory");
    }
    GBAR();
    #pragma unroll
    for (int ks = 0; ks < 2; ++ks) {
      short8 a, b[4];
      a = *(const short8*)(&As[cur][(wr * 16 + lr) * 64 +
                                    (((ks * 4 + lh) ^ (lr & 7)) * 8)]);
      #pragma unroll
      for (int n = 0; n < 4; ++n)
        b[n] = *(const short8*)(&Bs[cur][(wc * 64 + n * 16 + lr) * 64 +
                                         (((ks * 4 + lh) ^ (lr & 7)) * 8)]);
      #pragma unroll
      for (int n = 0; n < 4; ++n)
        acc[n] = __builtin_amdgcn_mfma_f32_16x16x32_bf16(a, b[n], acc[n], 0, 0, 0);
    }
    GBAR();
  }
  #pragma unroll
  for (int r = 0; r < 4; ++r) {
    const int row = m0 + wr * 16 + lh * 4 + r;
    #pragma unroll
    for (int n = 0; n < 4; ++n)
      outF[(size_t)row * N + n0 + wc * 64 + n * 16 + lr] = acc[n][r];
  }
}

// Flash attention (R17-best) + T13 defer-max (THR=8 in exp2 space): skip the
// O/o_l rescale unless some lane's tile-max grew by >8. P bounded by 2^8;
// bf16 relative precision is scale-free, numerics unchanged.
__global__ __launch_bounds__(256, 4) void attn_kernel(
    const bfu* __restrict__ qr, const bfu* __restrict__ kr,
    const bfu* __restrict__ vt, const unsigned char* __restrict__ allow,
    bfu* __restrict__ ao) {
  const int qb = 31 - blockIdx.x;  // heavy q-blocks first
  const int h = blockIdx.y, kv = h >> 2;
  const int t = threadIdx.x, wid = t >> 6, lane = t & 63;
  const int lr = lane & 15, lh = lane >> 4;
  const int q0 = qb * 64;
  const int qrow = q0 + wid * 16 + lr;
  __shared__ bfu KB[2][64 * 64];
  __shared__ bfu VB[2][64 * 64];
  __shared__ bfu P[4][16 * 64];
  bfu* Pw = P[wid];

  unsigned int amask = 0, emask = 0;
  for (int kb = 0; kb < 32; ++kb) {
    bool bm = allow[qb * 32 + kb] != 0;
    bool fw = (kb < 4) || (kb >= qb - 3 && kb <= qb - 1);
    bool ed = (kb == qb) || (kb == qb - 4);
    if (bm || fw || ed) {
      amask |= 1u << kb;
      if (!bm && !fw) emask |= 1u << kb;
    }
  }

  short8 bq[2];
  #pragma unroll
  for (int ks = 0; ks < 2; ++ks)
    bq[ks] = *(const short8*)(qr + ((size_t)h * TT + qrow) * 64 + ks * 32 + lh * 8);

  short8 vones;
  #pragma unroll
  for (int i = 0; i < 8; ++i) vones[i] = (short)0x3F80;  // bf16 1.0

  f32x4 o[4] = {};
  f32x4 o_l = {};
  float m_reg = -1e30f;

  auto stage = [&](bfu* buf, const bfu* gbase) {
    #pragma unroll
    for (int c = 0; c < 2; ++c) {
      int chunk = wid * 128 + c * 64 + lane;
      int row = chunk >> 3, s = chunk & 7;
      gload16(gbase + row * 64 + (s ^ (row & 7)) * 8,
              buf + (wid * 128 + c * 64) * 8);
    }
  };

  auto qk_tile = [&](const bfu* KBuf, int kb, f32x4 s[4]) {
    __builtin_amdgcn_s_setprio(1);
    #pragma unroll
    for (int j = 0; j < 4; ++j) {
      const int row = j * 16 + lr;
      short8 a0 = *(const short8*)(KBuf + row * 64 + ((lh    ) ^ (row & 7)) * 8);
      short8 a1 = *(const short8*)(KBuf + row * 64 + ((lh + 4) ^ (row & 7)) * 8);
      f32x4 z = {};
      z = __builtin_amdgcn_mfma_f32_16x16x32_bf16(a0, bq[0], z, 0, 0, 0);
      s[j] = __builtin_amdgcn_mfma_f32_16x16x32_bf16(a1, bq[1], z, 0, 0, 0);
    }
    __builtin_amdgcn_s_setprio(0);
    if ((emask >> kb) & 1) {
      #pragma unroll
      for (int j = 0; j < 4; ++j)
        #pragma unroll
        for (int reg = 0; reg < 4; ++reg) {
          int k = kb * 64 + j * 16 + lh * 4 + reg;
          bool ok = (k <= qrow && k >= qrow - 255) || (k < 256);
          if (!ok) s[j][reg] = -1e30f;
        }
    }
  };

  auto pv_tile = [&](const bfu* VBuf, f32x4 s[4]) {
    #pragma unroll
    for (int j = 0; j < 4; ++j) {
      unsigned int w0 = cvtpk(s[j][0], s[j][1]);
      unsigned int w1 = cvtpk(s[j][2], s[j][3]);
      int base = lr * 64 + (((j * 2 + (lh >> 1)) ^ (lr & 7)) * 8) + (lh & 1) * 4;
      *(unsigned int*)(Pw + base) = w0;
      *(unsigned int*)(Pw + base + 2) = w1;
    }
    short8 pa[2];
    #pragma unroll
    for (int ks = 0; ks < 2; ++ks)
      pa[ks] = *(const short8*)(Pw + lr * 64 + (((ks * 4 + lh) ^ (lr & 7)) * 8));
    __builtin_amdgcn_s_setprio(1);
    #pragma unroll
    for (int n = 0; n < 4; ++n) {
      #pragma unroll
      for (int ks = 0; ks < 2; ++ks) {
        const int row = n * 16 + lr;
        short8 bv = *(const short8*)(VBuf + row * 64 + ((ks * 4 + lh) ^ (row & 7)) * 8);
        o[n] = __builtin_amdgcn_mfma_f32_16x16x32_bf16(pa[ks], bv, o[n], 0, 0, 0);
      }
    }
    o_l = __builtin_amdgcn_mfma_f32_16x16x32_bf16(pa[0], vones, o_l, 0, 0, 0);
    o_l = __builtin_amdgcn_mfma_f32_16x16x32_bf16(pa[1], vones, o_l, 0, 0, 0);
    __builtin_amdgcn_s_setprio(0);
  };

  unsigned int am = amask;
  while (am) {
    const int k1 = __ffs(am) - 1; am &= am - 1;
    int k2 = -1;
    if (am) { k2 = __ffs(am) - 1; am &= am - 1; }

    __syncthreads();
    stage(KB[0], kr + ((size_t)kv * TT + k1 * 64) * 64);
    stage(VB[0], vt + ((size_t)k1 * 512 + kv * 64) * 64);
    if (k2 >= 0) {
      stage(KB[1], kr + ((size_t)kv * TT + k2 * 64) * 64);
      stage(VB[1], vt + ((size_t)k2 * 512 + kv * 64) * 64);
    }
    __syncthreads();

    f32x4 s1[4], s2[4];
    qk_tile(KB[0], k1, s1);
    if (k2 >= 0) qk_tile(KB[1], k2, s2);

    float mx = fmaxf(fmaxf(s1[0][0], s1[0][1]), fmaxf(s1[0][2], s1[0][3]));
    #pragma unroll
    for (int j = 1; j < 4; ++j)
      mx = fmaxf(mx, fmaxf(fmaxf(s1[j][0], s1[j][1]), fmaxf(s1[j][2], s1[j][3])));
    if (k2 >= 0) {
      #pragma unroll
      for (int j = 0; j < 4; ++j)
        mx = fmaxf(mx, fmaxf(fmaxf(s2[j][0], s2[j][1]), fmaxf(s2[j][2], s2[j][3])));
    }
    mx = fmaxf(mx, __shfl_xor(mx, 16));
    mx = fmaxf(mx, __shfl_xor(mx, 32));

    // T13 defer-max: only rescale when max grew by >8 (exp2 space).
    if (__any(mx > m_reg + 8.0f)) {
      float mnew = fmaxf(m_reg, mx);
      float corr = fexp2(m_reg - mnew);
      m_reg = mnew;
      #pragma unroll
      for (int r = 0; r < 4; ++r) {
        float cr = __shfl(corr, lh * 4 + r);
        #pragma unroll
        for (int n = 0; n < 4; ++n) o[n][r] *= cr;
        o_l[r] *= cr;
      }
    }

    #pragma unroll
    for (int j = 0; j < 4; ++j)
      #pragma unroll
      for (int reg = 0; reg < 4; ++reg)
        s1[j][reg] = fexp2(s1[j][reg] - m_reg);
    if (k2 >= 0) {
      #pragma unroll
      for (int j = 0; j < 4; ++j)
        #pragma unroll
        for (int reg = 0; reg < 4; ++reg)
          s2[j][reg] = fexp2(s2[j][reg] - m_reg);
    }

    pv_tile(VB[0], s1);
    if (k2 >= 0) pv_tile(VB[1], s2);
  }

  #pragma unroll
  for (int r = 0; r < 4; ++r) {
    float inv = 1.0f / o_l[r];
    #pragma unroll
    for (int n = 0; n < 4; ++n) {
      float val = o[n][r] * inv;
      ao[(size_t)(q0 + wid * 16 + lh * 4 + r) * EE + h * 64 + n * 16 + lr] = f2bf(val);
    }
  }
}

extern "C" void kernel_launch(void* const* d_in, const int* in_sizes, int n_in,
                              void* d_out, int out_size, void* d_ws, size_t ws_size,
                              hipStream_t stream) {
  const float* hs   = (const float*)d_in[0];
  const float* cosb = (const float*)d_in[1];
  const float* sinb = (const float*)d_in[2];
  const float* Wq   = (const float*)d_in[3];
  const float* Wk   = (const float*)d_in[4];
  const float* Wv   = (const float*)d_in[5];
  const float* Wo   = (const float*)d_in[6];
  const unsigned char* allow_raw = (const unsigned char*)d_in[7];
  float* out = (float*)d_out;

  char* ws = (char*)d_ws;
  const size_t MB = 1024 * 1024;
  bfu* hsb = (bfu*)(ws);            // [2048][2048] 8 MB (reused as ao later)
  bfu* wqb = (bfu*)(ws + 8 * MB);   // 8 MB
  bfu* wkb = (bfu*)(ws + 16 * MB);  // 2 MB
  bfu* wvb = (bfu*)(ws + 18 * MB);  // 2 MB
  bfu* wob = (bfu*)(ws + 20 * MB);  // 8 MB
  bfu* qr  = (bfu*)(ws + 28 * MB);  // [32][2048][64] 8 MB
  bfu* kr  = (bfu*)(ws + 36 * MB);  // [8][2048][64]  2 MB
  bfu* vt  = (bfu*)(ws + 38 * MB);  // [32][512][64]  2 MB (tile-major)
  unsigned char* maskc = (unsigned char*)(ws + 40 * MB);  // 1 KB
  bfu* ao = hsb;

  cvt5<<<dim3(1024, 5), 256, 0, stream>>>(hs, Wq, Wk, Wv,
                                          hsb, wqb, wkb, wvb,
                                          allow_raw, maskc);

  const float QSC = 0.125f * 1.44269504088896f;  // head scale * log2(e)
  gemm_qkv<<<dim3(24, 32), 512, 0, stream>>>(
      hsb, wqb, wkb, wvb, qr, kr, vt, cosb, sinb, QSC, Wo, wob);

  attn_kernel<<<dim3(32, 32), 256, 0, stream>>>(qr, kr, vt, maskc, ao);

  gemm_o<<<dim3(16, 32), 512, 0, stream>>>(ao, wob, out, 2048, 2048, 2048);
}